// Round 10
// baseline (181.796 us; speedup 1.0000x reference)
//
#include <hip/hip_runtime.h>
#include <hip/hip_bf16.h>
#include <stdint.h>

// ---------------------------------------------------------------------------
// RelativeCrossAttention: B=4, SQ=SKV=1024, D=1024, H=16, HD=64, MAXL=1024
// Round 10: R8 (proven) + Ts in bf16 [4][80][16] (cvt_pk pair writes).
// LDS 66.5KB -> 53.76KB -> 3 blocks/CU. DMA-staging (R9's other change)
// reverted pending bisection. GEMMs/prep identical to R8.
// ---------------------------------------------------------------------------

typedef __attribute__((ext_vector_type(8))) short short8;
typedef __attribute__((ext_vector_type(4))) float f32x4;

constexpr int Bz = 4, SQv = 1024, SKVv = 1024, Dv = 1024, Hv = 16, HDv = 64;
constexpr float LOG2E = 1.4426950408889634f;
constexpr float C1 = 0.125f * LOG2E;     // SCALE * log2e (QK path)
constexpr float THR2 = 11.5f;            // defer-max threshold (log2 units)

// workspace offsets (bytes)
constexpr size_t OFF_QB  = 0;
constexpr size_t OFF_KVB = 8388608;
constexpr size_t OFF_WQT = 16777216;
constexpr size_t OFF_WKT = 18874368;
constexpr size_t OFF_WVT = 20971520;
constexpr size_t OFF_WOT = 23068672;
constexpr size_t OFF_REL = 25165824;   // rel*log2e bf16 [2048][64]
constexpr size_t OFF_Q   = 25427968;
constexpr size_t OFF_K   = 33816576;
constexpr size_t OFF_V   = 42205184;   // V^T bf16 [(b*16+h)*64+d][1024]
constexpr size_t OFF_AO  = 50593792;

__device__ __forceinline__ unsigned short f2bf(float f) {
  union { float f; unsigned int u; } v; v.f = f;
  unsigned int r = (v.u + 0x7fffu + ((v.u >> 16) & 1u)) >> 16;
  return (unsigned short)r;
}

__device__ __forceinline__ float bf2f(unsigned short u) {
  union { unsigned int i; float f; } v; v.i = (unsigned int)u << 16;
  return v.f;
}

__device__ __forceinline__ unsigned short cvtpk1(float x) {
  unsigned int r;
  asm("v_cvt_pk_bf16_f32 %0, %1, %1" : "=v"(r) : "v"(x));
  return (unsigned short)r;
}

__device__ __forceinline__ unsigned int cvtpk2(float lo, float hi) {
  unsigned int r;
  asm("v_cvt_pk_bf16_f32 %0, %1, %2" : "=v"(r) : "v"(lo), "v"(hi));
  return r;
}

__device__ __forceinline__ void gload_lds16(const unsigned short* g, unsigned short* l) {
  __builtin_amdgcn_global_load_lds(
      (const __attribute__((address_space(1))) unsigned int*)g,
      (__attribute__((address_space(3))) unsigned int*)l, 16, 0, 0);
}

template <int CTRL>
__device__ __forceinline__ float dpp_ror(float v) {
  int x = __builtin_amdgcn_update_dpp(__builtin_bit_cast(int, v),
                                      __builtin_bit_cast(int, v),
                                      CTRL, 0xf, 0xf, false);
  return __builtin_bit_cast(float, x);
}
__device__ __forceinline__ float red16_max(float v) {
  v = fmaxf(v, dpp_ror<0x121>(v));
  v = fmaxf(v, dpp_ror<0x122>(v));
  v = fmaxf(v, dpp_ror<0x124>(v));
  v = fmaxf(v, dpp_ror<0x128>(v));
  return v;
}
__device__ __forceinline__ float red16_sum(float v) {
  v += dpp_ror<0x121>(v);
  v += dpp_ror<0x122>(v);
  v += dpp_ror<0x124>(v);
  v += dpp_ror<0x128>(v);
  return v;
}

// ---------------- fused prep: cvt q/kv/rel + transpose 4 weights -----------
__global__ __launch_bounds__(256) void k_prep(const float* __restrict__ q,
                                              const float* __restrict__ kv,
                                              const float* __restrict__ rel,
                                              const float* __restrict__ Wq,
                                              const float* __restrict__ Wk,
                                              const float* __restrict__ Wv,
                                              const float* __restrict__ Wo,
                                              unsigned short* __restrict__ qb,
                                              unsigned short* __restrict__ kvb,
                                              unsigned short* __restrict__ relb,
                                              unsigned short* __restrict__ Wqt,
                                              unsigned short* __restrict__ Wkt,
                                              unsigned short* __restrict__ Wvt,
                                              unsigned short* __restrict__ Wot) {
  __shared__ unsigned short t[64][72];
  const int bx = blockIdx.x;
  if (bx < 4096) {
    const float* s = bx < 2048 ? q : kv;
    unsigned short* d = bx < 2048 ? qb : kvb;
    const int base = (bx & 2047) * 2048 + threadIdx.x * 8;
    float4 f0 = *(const float4*)(s + base);
    float4 f1 = *(const float4*)(s + base + 4);
    unsigned short o[8] = {f2bf(f0.x), f2bf(f0.y), f2bf(f0.z), f2bf(f0.w),
                           f2bf(f1.x), f2bf(f1.y), f2bf(f1.z), f2bf(f1.w)};
    *(uint4*)(d + base) = *(const uint4*)o;
    return;
  }
  if (bx < 4160) {
    const int i = (bx - 4096) * 2048 + threadIdx.x * 8;
    const int nsrc = 2047 * 64;
    unsigned short o[8];
    if (i + 8 <= nsrc) {
      float4 f0 = *(const float4*)(rel + i);
      float4 f1 = *(const float4*)(rel + i + 4);
      o[0]=f2bf(f0.x*LOG2E); o[1]=f2bf(f0.y*LOG2E); o[2]=f2bf(f0.z*LOG2E); o[3]=f2bf(f0.w*LOG2E);
      o[4]=f2bf(f1.x*LOG2E); o[5]=f2bf(f1.y*LOG2E); o[6]=f2bf(f1.z*LOG2E); o[7]=f2bf(f1.w*LOG2E);
    } else {
#pragma unroll
      for (int k = 0; k < 8; k++) o[k] = (i + k < nsrc) ? f2bf(rel[i + k]*LOG2E) : (unsigned short)0;
    }
    *(uint4*)(relb + i) = *(const uint4*)o;
    return;
  }
  const int tt = bx - 4160;
  const int z = tt >> 8, tile = tt & 255;
  const float* W = z == 0 ? Wq : z == 1 ? Wk : z == 2 ? Wv : Wo;
  unsigned short* Wt = z == 0 ? Wqt : z == 1 ? Wkt : z == 2 ? Wvt : Wot;
  const int r0 = (tile >> 4) * 64, c0 = (tile & 15) * 64;
  const int tid = threadIdx.x;
  const int r = tid >> 2, cc = (tid & 3) * 16;
  const float* src = W + (size_t)(r0 + r) * Dv + c0 + cc;
#pragma unroll
  for (int i = 0; i < 16; i += 4) {
    float4 f = *(const float4*)(src + i);
    t[r][cc + i + 0] = f2bf(f.x);
    t[r][cc + i + 1] = f2bf(f.y);
    t[r][cc + i + 2] = f2bf(f.z);
    t[r][cc + i + 3] = f2bf(f.w);
  }
  __syncthreads();
  unsigned short tmp[16];
#pragma unroll
  for (int i = 0; i < 16; i++) tmp[i] = t[cc + i][r];
  unsigned short* dstp = Wt + (size_t)(c0 + r) * Dv + r0 + cc;
  *(uint4*)(dstp)     = *(const uint4*)&tmp[0];
  *((uint4*)dstp + 1) = *(const uint4*)&tmp[8];
}

// ---------------- merged QKV NT GEMM (z = 0,1,2), 128x128 tile -------------
__global__ __launch_bounds__(256) void k_gemm3(const unsigned short* __restrict__ qb,
                                               const unsigned short* __restrict__ kvb,
                                               const unsigned short* __restrict__ Wqt,
                                               const unsigned short* __restrict__ Wkt,
                                               const unsigned short* __restrict__ Wvt,
                                               const float* __restrict__ bq,
                                               const float* __restrict__ bk,
                                               const float* __restrict__ bv,
                                               unsigned short* __restrict__ Qb,
                                               unsigned short* __restrict__ Kb,
                                               unsigned short* __restrict__ Vtb) {
  __shared__ unsigned short As[128 * 32];
  __shared__ unsigned short Bs[128 * 32];
  const int z = blockIdx.z;
  const unsigned short* A  = z == 0 ? qb : kvb;
  const unsigned short* Bt = z == 0 ? Wqt : z == 1 ? Wkt : Wvt;
  const float* bias        = z == 0 ? bq : z == 1 ? bk : bv;
  unsigned short* Cout     = z == 0 ? Qb : z == 1 ? Kb : Vtb;
  const int K = Dv, N = Dv;

  const int tid = threadIdx.x;
  const int l = tid & 63, w = tid >> 6;
  const int wr = w >> 1, wc = w & 1;
  const int m0 = blockIdx.y * 128, n0 = blockIdx.x * 128;
  const int lr = l & 15, kk = (l >> 4) * 8;
  const int srow = tid >> 2, soff = (tid & 3) * 8;

  const unsigned short* Ag = A + (size_t)(m0 + srow) * K + soff;
  const unsigned short* Bg = Bt + (size_t)(n0 + srow) * K + soff;
  unsigned short* AsD = &As[tid * 8];
  unsigned short* BsD = &Bs[tid * 8];

  f32x4 acc[4][4] = {};

  for (int k0 = 0; k0 < K; k0 += 32) {
    __syncthreads();
    gload_lds16(Ag + k0, AsD);
    gload_lds16(Ag + (size_t)64 * K + k0, AsD + 2048);
    gload_lds16(Bg + k0, BsD);
    gload_lds16(Bg + (size_t)64 * K + k0, BsD + 2048);
    __syncthreads();
    short8 af[4], bf[4];
#pragma unroll
    for (int m = 0; m < 4; m++) af[m] = *(const short8*)&As[(wr * 64 + m * 16 + lr) * 32 + kk];
#pragma unroll
    for (int n = 0; n < 4; n++) bf[n] = *(const short8*)&Bs[(wc * 64 + n * 16 + lr) * 32 + kk];
    __builtin_amdgcn_s_setprio(1);
#pragma unroll
    for (int m = 0; m < 4; m++)
#pragma unroll
      for (int n = 0; n < 4; n++)
        acc[m][n] = __builtin_amdgcn_mfma_f32_16x16x32_bf16(af[m], bf[n], acc[m][n], 0, 0, 0);
    __builtin_amdgcn_s_setprio(0);
  }

#pragma unroll
  for (int m = 0; m < 4; m++) {
    const int row_base = m0 + wr * 64 + m * 16 + (l >> 4) * 4;
#pragma unroll
    for (int n = 0; n < 4; n++) {
      const int col = n0 + wc * 64 + n * 16 + lr;
      const float bv4 = bias[col];
      if (z == 2) {
        const int h = col >> 6, hd = col & 63;
        const int bb = row_base >> 10, j = row_base & 1023;
        unsigned short t4[4];
#pragma unroll
        for (int r = 0; r < 4; r++) t4[r] = f2bf(acc[m][n][r] + bv4);
        *(uint2*)&Cout[((size_t)((bb * 16 + h) * 64 + hd)) * 1024 + j] = *(const uint2*)t4;
      } else {
#pragma unroll
        for (int r = 0; r < 4; r++)
          Cout[(size_t)(row_base + r) * N + col] = f2bf(acc[m][n][r] + bv4);
      }
    }
  }
}

// ---------------- O-proj NT GEMM: 64x128 tile, fp32 out --------------------
__global__ __launch_bounds__(256) void k_gemmO(const unsigned short* __restrict__ A,
                                               const unsigned short* __restrict__ Bt,
                                               const float* __restrict__ bias,
                                               float* __restrict__ Cout) {
  __shared__ unsigned short As[64 * 32];
  __shared__ unsigned short Bs[128 * 32];
  const int K = Dv, N = Dv;
  const int tid = threadIdx.x;
  const int l = tid & 63, w = tid >> 6;
  const int wr = w >> 1, wc = w & 1;
  const int m0 = blockIdx.y * 64, n0 = blockIdx.x * 128;
  const int lr = l & 15, kk = (l >> 4) * 8;
  const int srow = tid >> 2, soff = (tid & 3) * 8;

  const unsigned short* Ag = A + (size_t)(m0 + srow) * K + soff;
  const unsigned short* Bg = Bt + (size_t)(n0 + srow) * K + soff;
  unsigned short* AsD = &As[tid * 8];
  unsigned short* BsD = &Bs[tid * 8];

  f32x4 acc[2][4] = {};

  for (int k0 = 0; k0 < K; k0 += 32) {
    __syncthreads();
    gload_lds16(Ag + k0, AsD);
    gload_lds16(Bg + k0, BsD);
    gload_lds16(Bg + (size_t)64 * K + k0, BsD + 2048);
    __syncthreads();
    short8 af[2], bf[4];
#pragma unroll
    for (int m = 0; m < 2; m++) af[m] = *(const short8*)&As[(wr * 32 + m * 16 + lr) * 32 + kk];
#pragma unroll
    for (int n = 0; n < 4; n++) bf[n] = *(const short8*)&Bs[(wc * 64 + n * 16 + lr) * 32 + kk];
    __builtin_amdgcn_s_setprio(1);
#pragma unroll
    for (int m = 0; m < 2; m++)
#pragma unroll
      for (int n = 0; n < 4; n++)
        acc[m][n] = __builtin_amdgcn_mfma_f32_16x16x32_bf16(af[m], bf[n], acc[m][n], 0, 0, 0);
    __builtin_amdgcn_s_setprio(0);
  }

#pragma unroll
  for (int m = 0; m < 2; m++) {
    const int row_base = m0 + wr * 32 + m * 16 + (l >> 4) * 4;
#pragma unroll
    for (int n = 0; n < 4; n++) {
      const int col = n0 + wc * 64 + n * 16 + lr;
      const float bv4 = bias[col];
#pragma unroll
      for (int r = 0; r < 4; r++)
        Cout[(size_t)(row_base + r) * N + col] = acc[m][n][r] + bv4;
    }
  }
}

// ---------------- fused attention ------------------------------------------
// grid 1024 (XCD-chunk swizzled), 256 thr (4 waves). Wave w: 16 q-rows.
// K,V double-buffered LDS (T14 split, 1 barrier/iter); rel loads hoisted.
// Ts transposed-unshifted bf16 [tb][rr] (cvt_pk uint2 writes); shared max.
__global__ __launch_bounds__(256) void k_attn(const unsigned short* __restrict__ Qb,
                                              const unsigned short* __restrict__ Kb,
                                              const unsigned short* __restrict__ Vt,
                                              const unsigned short* __restrict__ relb,
                                              unsigned short* __restrict__ AO) {
  __shared__ unsigned short Ks[2][64][68];   // 17,408 B
  __shared__ unsigned short Vs[2][64][68];   // 17,408 B (Vt rows: [d][j])
  __shared__ unsigned short Tsb[4][80][16];  // 10,240 B, bf16 [tb][rr]
  __shared__ unsigned short Ps[4][16][68];   //  8,704 B   -> total 53,760 B

  const int tid = threadIdx.x, l = tid & 63, w = tid >> 6;
  const int lr = l & 15, lg = l >> 4, kk = lg * 8;

  // bijective XCD-chunk swizzle: XCD k gets 8 heads' K/V (2MB) -> L2-resident
  const int raw = blockIdx.x;
  const int work = (raw & 7) * 128 + (raw >> 3);
  const int i0 = (work & 15) * 64;
  const int h = (work >> 4) & 15;
  const int b = work >> 8;

  const unsigned short* Kg  = Kb + (size_t)b * SKVv * Dv + h * HDv;
  const unsigned short* Vtg = Vt + ((size_t)(b * Hv + h) * HDv) * (size_t)SKVv;

  const unsigned short* Qg = Qb + ((size_t)(b * SQv + i0 + w * 16 + lr)) * Dv + h * HDv;
  short8 aq0 = *(const short8*)&Qg[kk];
  short8 aq1 = *(const short8*)&Qg[32 + kk];

  // staging coords: thread covers K row j0+sr / Vt row d=sr, 32B chunk sc
  const int sr = tid >> 2, sc = (tid & 3) * 16;

  // strength-reduced running pointers (next K/V tile to load)
  const unsigned short* kld = Kg + (size_t)(64 + sr) * Dv + sc;
  const unsigned short* vld = Vtg + (size_t)sr * SKVv + 64 + sc;
  // rel band pointer for tile 0: row (i0 - 0 + 960 + w*16 + lr)
  const unsigned short* relit = relb + (size_t)(i0 + 960 + w * 16 + lr) * HDv + kk;

  uint4 pk0, pk1, pv0, pv1;
  auto wrbuf = [&](int buf) {
    *(uint4*)&Ks[buf][sr][sc]     = pk0;
    *(uint4*)&Ks[buf][sr][sc + 8] = pk1;
    *(uint4*)&Vs[buf][sr][sc]     = pv0;
    *(uint4*)&Vs[buf][sr][sc + 8] = pv1;
  };

  // prologue: tile 0
  pk0 = *(const uint4*)&Kg[(size_t)sr * Dv + sc];
  pk1 = *(const uint4*)&Kg[(size_t)sr * Dv + sc + 8];
  pv0 = *(const uint4*)&Vtg[(size_t)sr * SKVv + sc];
  pv1 = *(const uint4*)&Vtg[(size_t)sr * SKVv + sc + 8];
  wrbuf(0);
  __syncthreads();

  f32x4 Oacc[4] = {};
  f32x4 vsum[4] = {};   // vsum[jf][r] (deferred denominator)
  float mrow = -3e38f;  // shared over this lane-group's 4 rows

  for (int it = 0; it < 16; ++it) {
    const int cur = it & 1;
    if (it < 15) {       // T14: issue next-tile loads early, write late
      pk0 = *(const uint4*)&kld[0];
      pk1 = *(const uint4*)&kld[8];
      pv0 = *(const uint4*)&vld[0];
      pv1 = *(const uint4*)&vld[8];
      kld += (size_t)64 * Dv;
      vld += 64;
    }

    // hoisted rel-band fragment loads (L2-resident; hide under QK MFMAs)
    short8 br0[5], br1[5];
#pragma unroll
    for (int tf = 0; tf < 5; tf++) {
      br0[tf] = *(const short8*)&relit[(size_t)tf * 16 * HDv];
      br1[tf] = *(const short8*)&relit[(size_t)tf * 16 * HDv + 32];
    }
    relit -= (size_t)64 * HDv;   // next iter: base drops by 64 rows

    // ---- content scores S = Q K^T ----
    __builtin_amdgcn_s_setprio(1);
    f32x4 sacc[4] = {};
#pragma unroll
    for (int jf = 0; jf < 4; jf++) {
      short8 bk0 = *(const short8*)&Ks[cur][jf * 16 + lr][kk];
      short8 bk1 = *(const short8*)&Ks[cur][jf * 16 + lr][32 + kk];
      sacc[jf] = __builtin_amdgcn_mfma_f32_16x16x32_bf16(aq0, bk0, sacc[jf], 0, 0, 0);
      sacc[jf] = __builtin_amdgcn_mfma_f32_16x16x32_bf16(aq1, bk1, sacc[jf], 0, 0, 0);
    }

    // ---- rel band T -> Tsb[w][tb][rr] bf16, one uint2 write per tf ----
#pragma unroll
    for (int tf = 0; tf < 5; tf++) {
      f32x4 tacc = {};
      tacc = __builtin_amdgcn_mfma_f32_16x16x32_bf16(aq0, br0[tf], tacc, 0, 0, 0);
      tacc = __builtin_amdgcn_mfma_f32_16x16x32_bf16(aq1, br1[tf], tacc, 0, 0, 0);
      uint2 pk;
      pk.x = cvtpk2(tacc[0], tacc[1]);
      pk.y = cvtpk2(tacc[2], tacc[3]);
      *(uint2*)&Tsb[w][tf * 16 + lr][4 * lg] = pk;
    }
    __builtin_amdgcn_s_setprio(0);

    // ---- combine + softmax (log2 domain, shared max, defer-max) ----
    float p[4][4];
#pragma unroll
    for (int jf = 0; jf < 4; jf++) {
      const int jj = jf * 16 + lr;
#pragma unroll
      for (int r = 0; r < 4; r++) {
        const int rr = lg * 4 + r;
        p[jf][r] = sacc[jf][r] * C1 + bf2f(Tsb[w][rr - jj + 63][rr]);
      }
    }
    float mx = p[0][0];
#pragma unroll
    for (int jf = 0; jf < 4; jf++)
#pragma unroll
      for (int r = 0; r < 4; r++) mx = fmaxf(mx, p[jf][r]);
    mx = red16_max(mx);
    if (__any(mx > mrow + THR2)) {
      const float mnew = fmaxf(mrow, mx);
      const float rs = __builtin_amdgcn_exp2f(mrow - mnew);
      mrow = mnew;
#pragma unroll
      for (int q4 = 0; q4 < 4; q4++) { vsum[q4] *= rs; Oacc[q4] *= rs; }
    }
#pragma unroll
    for (int jf = 0; jf < 4; jf++)
#pragma unroll
      for (int r = 0; r < 4; r++) {
        const float e = __builtin_amdgcn_exp2f(p[jf][r] - mrow);
        vsum[jf][r] += e;
        Ps[w][lg * 4 + r][jf * 16 + lr] = cvtpk1(e);
      }

    // ---- O += P V ----
    short8 ap0 = *(const short8*)&Ps[w][lr][kk];
    short8 ap1 = *(const short8*)&Ps[w][lr][32 + kk];
    __builtin_amdgcn_s_setprio(1);
#pragma unroll
    for (int df = 0; df < 4; df++) {
      short8 bv0 = *(const short8*)&Vs[cur][df * 16 + lr][kk];
      short8 bv1 = *(const short8*)&Vs[cur][df * 16 + lr][32 + kk];
      Oacc[df] = __builtin_amdgcn_mfma_f32_16x16x32_bf16(ap0, bv0, Oacc[df], 0, 0, 0);
      Oacc[df] = __builtin_amdgcn_mfma_f32_16x16x32_bf16(ap1, bv1, Oacc[df], 0, 0, 0);
    }
    __builtin_amdgcn_s_setprio(0);

    if (it < 15) wrbuf(cur ^ 1);  // write-late half of T14 split
    __syncthreads();
  }

  // ---- epilogue: deferred denominator, normalize, write ----
#pragma unroll
  for (int r = 0; r < 4; r++) {
    float s = vsum[0][r] + vsum[1][r] + vsum[2][r] + vsum[3][r];
    s = red16_sum(s);
    const float inv = 1.f / s;
    const size_t row = (size_t)(b * SQv + i0 + w * 16 + lg * 4 + r) * Dv + h * HDv;
#pragma unroll
    for (int df = 0; df < 4; df++)
      AO[row + df * 16 + lr] = cvtpk1(Oacc[df][r] * inv);
  }
}

// ---------------------------------------------------------------------------
extern "C" void kernel_launch(void* const* d_in, const int* in_sizes, int n_in,
                              void* d_out, int out_size, void* d_ws, size_t ws_size,
                              hipStream_t stream) {
  const float* query = (const float*)d_in[0];
  const float* keyv  = (const float*)d_in[1];
  const float* Wq    = (const float*)d_in[2];
  const float* bq    = (const float*)d_in[3];
  const float* Wk    = (const float*)d_in[4];
  const float* bk    = (const float*)d_in[5];
  const float* Wv    = (const float*)d_in[6];
  const float* bv    = (const float*)d_in[7];
  const float* Wo    = (const float*)d_in[8];
  const float* bo    = (const float*)d_in[9];
  const float* rel   = (const float*)d_in[10];

  char* ws = (char*)d_ws;
  unsigned short* qb   = (unsigned short*)(ws + OFF_QB);
  unsigned short* kvb  = (unsigned short*)(ws + OFF_KVB);
  unsigned short* Wqt  = (unsigned short*)(ws + OFF_WQT);
  unsigned short* Wkt  = (unsigned short*)(ws + OFF_WKT);
  unsigned short* Wvt  = (unsigned short*)(ws + OFF_WVT);
  unsigned short* Wot  = (unsigned short*)(ws + OFF_WOT);
  unsigned short* relb = (unsigned short*)(ws + OFF_REL);
  unsigned short* Qb   = (unsigned short*)(ws + OFF_Q);
  unsigned short* Kb   = (unsigned short*)(ws + OFF_K);
  unsigned short* Vtb  = (unsigned short*)(ws + OFF_V);
  unsigned short* AOb  = (unsigned short*)(ws + OFF_AO);

  k_prep<<<5184, 256, 0, stream>>>(query, keyv, rel, Wq, Wk, Wv, Wo,
                                   qb, kvb, relb, Wqt, Wkt, Wvt, Wot);

  dim3 g3(Dv / 128, (Bz * SQv) / 128, 3);  // 768 blocks
  k_gemm3<<<g3, 256, 0, stream>>>(qb, kvb, Wqt, Wkt, Wvt, bq, bk, bv, Qb, Kb, Vtb);

  k_attn<<<1024, 256, 0, stream>>>(Qb, Kb, Vtb, relb, AOb);

  dim3 go(Dv / 128, (Bz * SQv) / 64);  // 512 blocks
  k_gemmO<<<go, 256, 0, stream>>>(AOb, Wot, bo, (float*)d_out);
}

// Round 12
// 174.420 us; speedup vs baseline: 1.0423x; 1.0423x over previous
//
#include <hip/hip_runtime.h>
#include <hip/hip_bf16.h>
#include <stdint.h>

// ---------------------------------------------------------------------------
// RelativeCrossAttention: B=4, SQ=SKV=1024, D=1024, H=16, HD=64, MAXL=1024
// Round 12: R8 (proven base) + Ts bf16 at proven [18] stride (cvtpk2 u32
// writes; R10-proven values, R8-proven banking) + rel loads issued before
// K/V prefetch (vmcnt FIFO: Ts wait no longer drains K/V). R11's 2-M-frag
// restructure abandoned (3rd unexplained restructure failure).
// GEMMs/prep identical to R8.
// ---------------------------------------------------------------------------

typedef __attribute__((ext_vector_type(8))) short short8;
typedef __attribute__((ext_vector_type(4))) float f32x4;

constexpr int Bz = 4, SQv = 1024, SKVv = 1024, Dv = 1024, Hv = 16, HDv = 64;
constexpr float LOG2E = 1.4426950408889634f;
constexpr float C1 = 0.125f * LOG2E;     // SCALE * log2e (QK path)
constexpr float THR2 = 11.5f;            // defer-max threshold (log2 units)

// workspace offsets (bytes)
constexpr size_t OFF_QB  = 0;
constexpr size_t OFF_KVB = 8388608;
constexpr size_t OFF_WQT = 16777216;
constexpr size_t OFF_WKT = 18874368;
constexpr size_t OFF_WVT = 20971520;
constexpr size_t OFF_WOT = 23068672;
constexpr size_t OFF_REL = 25165824;   // rel*log2e bf16 [2048][64]
constexpr size_t OFF_Q   = 25427968;
constexpr size_t OFF_K   = 33816576;
constexpr size_t OFF_V   = 42205184;   // V^T bf16 [(b*16+h)*64+d][1024]
constexpr size_t OFF_AO  = 50593792;

__device__ __forceinline__ unsigned short f2bf(float f) {
  union { float f; unsigned int u; } v; v.f = f;
  unsigned int r = (v.u + 0x7fffu + ((v.u >> 16) & 1u)) >> 16;
  return (unsigned short)r;
}

__device__ __forceinline__ float bf2f(unsigned short u) {
  union { unsigned int i; float f; } v; v.i = (unsigned int)u << 16;
  return v.f;
}

__device__ __forceinline__ unsigned short cvtpk1(float x) {
  unsigned int r;
  asm("v_cvt_pk_bf16_f32 %0, %1, %1" : "=v"(r) : "v"(x));
  return (unsigned short)r;
}

__device__ __forceinline__ unsigned int cvtpk2(float lo, float hi) {
  unsigned int r;
  asm("v_cvt_pk_bf16_f32 %0, %1, %2" : "=v"(r) : "v"(lo), "v"(hi));
  return r;
}

__device__ __forceinline__ void gload_lds16(const unsigned short* g, unsigned short* l) {
  __builtin_amdgcn_global_load_lds(
      (const __attribute__((address_space(1))) unsigned int*)g,
      (__attribute__((address_space(3))) unsigned int*)l, 16, 0, 0);
}

template <int CTRL>
__device__ __forceinline__ float dpp_ror(float v) {
  int x = __builtin_amdgcn_update_dpp(__builtin_bit_cast(int, v),
                                      __builtin_bit_cast(int, v),
                                      CTRL, 0xf, 0xf, false);
  return __builtin_bit_cast(float, x);
}
__device__ __forceinline__ float red16_max(float v) {
  v = fmaxf(v, dpp_ror<0x121>(v));
  v = fmaxf(v, dpp_ror<0x122>(v));
  v = fmaxf(v, dpp_ror<0x124>(v));
  v = fmaxf(v, dpp_ror<0x128>(v));
  return v;
}
__device__ __forceinline__ float red16_sum(float v) {
  v += dpp_ror<0x121>(v);
  v += dpp_ror<0x122>(v);
  v += dpp_ror<0x124>(v);
  v += dpp_ror<0x128>(v);
  return v;
}

// ---------------- fused prep: cvt q/kv/rel + transpose 4 weights -----------
__global__ __launch_bounds__(256) void k_prep(const float* __restrict__ q,
                                              const float* __restrict__ kv,
                                              const float* __restrict__ rel,
                                              const float* __restrict__ Wq,
                                              const float* __restrict__ Wk,
                                              const float* __restrict__ Wv,
                                              const float* __restrict__ Wo,
                                              unsigned short* __restrict__ qb,
                                              unsigned short* __restrict__ kvb,
                                              unsigned short* __restrict__ relb,
                                              unsigned short* __restrict__ Wqt,
                                              unsigned short* __restrict__ Wkt,
                                              unsigned short* __restrict__ Wvt,
                                              unsigned short* __restrict__ Wot) {
  __shared__ unsigned short t[64][72];
  const int bx = blockIdx.x;
  if (bx < 4096) {
    const float* s = bx < 2048 ? q : kv;
    unsigned short* d = bx < 2048 ? qb : kvb;
    const int base = (bx & 2047) * 2048 + threadIdx.x * 8;
    float4 f0 = *(const float4*)(s + base);
    float4 f1 = *(const float4*)(s + base + 4);
    unsigned short o[8] = {f2bf(f0.x), f2bf(f0.y), f2bf(f0.z), f2bf(f0.w),
                           f2bf(f1.x), f2bf(f1.y), f2bf(f1.z), f2bf(f1.w)};
    *(uint4*)(d + base) = *(const uint4*)o;
    return;
  }
  if (bx < 4160) {
    const int i = (bx - 4096) * 2048 + threadIdx.x * 8;
    const int nsrc = 2047 * 64;
    unsigned short o[8];
    if (i + 8 <= nsrc) {
      float4 f0 = *(const float4*)(rel + i);
      float4 f1 = *(const float4*)(rel + i + 4);
      o[0]=f2bf(f0.x*LOG2E); o[1]=f2bf(f0.y*LOG2E); o[2]=f2bf(f0.z*LOG2E); o[3]=f2bf(f0.w*LOG2E);
      o[4]=f2bf(f1.x*LOG2E); o[5]=f2bf(f1.y*LOG2E); o[6]=f2bf(f1.z*LOG2E); o[7]=f2bf(f1.w*LOG2E);
    } else {
#pragma unroll
      for (int k = 0; k < 8; k++) o[k] = (i + k < nsrc) ? f2bf(rel[i + k]*LOG2E) : (unsigned short)0;
    }
    *(uint4*)(relb + i) = *(const uint4*)o;
    return;
  }
  const int tt = bx - 4160;
  const int z = tt >> 8, tile = tt & 255;
  const float* W = z == 0 ? Wq : z == 1 ? Wk : z == 2 ? Wv : Wo;
  unsigned short* Wt = z == 0 ? Wqt : z == 1 ? Wkt : z == 2 ? Wvt : Wot;
  const int r0 = (tile >> 4) * 64, c0 = (tile & 15) * 64;
  const int tid = threadIdx.x;
  const int r = tid >> 2, cc = (tid & 3) * 16;
  const float* src = W + (size_t)(r0 + r) * Dv + c0 + cc;
#pragma unroll
  for (int i = 0; i < 16; i += 4) {
    float4 f = *(const float4*)(src + i);
    t[r][cc + i + 0] = f2bf(f.x);
    t[r][cc + i + 1] = f2bf(f.y);
    t[r][cc + i + 2] = f2bf(f.z);
    t[r][cc + i + 3] = f2bf(f.w);
  }
  __syncthreads();
  unsigned short tmp[16];
#pragma unroll
  for (int i = 0; i < 16; i++) tmp[i] = t[cc + i][r];
  unsigned short* dstp = Wt + (size_t)(c0 + r) * Dv + r0 + cc;
  *(uint4*)(dstp)     = *(const uint4*)&tmp[0];
  *((uint4*)dstp + 1) = *(const uint4*)&tmp[8];
}

// ---------------- merged QKV NT GEMM (z = 0,1,2), 128x128 tile -------------
__global__ __launch_bounds__(256) void k_gemm3(const unsigned short* __restrict__ qb,
                                               const unsigned short* __restrict__ kvb,
                                               const unsigned short* __restrict__ Wqt,
                                               const unsigned short* __restrict__ Wkt,
                                               const unsigned short* __restrict__ Wvt,
                                               const float* __restrict__ bq,
                                               const float* __restrict__ bk,
                                               const float* __restrict__ bv,
                                               unsigned short* __restrict__ Qb,
                                               unsigned short* __restrict__ Kb,
                                               unsigned short* __restrict__ Vtb) {
  __shared__ unsigned short As[128 * 32];
  __shared__ unsigned short Bs[128 * 32];
  const int z = blockIdx.z;
  const unsigned short* A  = z == 0 ? qb : kvb;
  const unsigned short* Bt = z == 0 ? Wqt : z == 1 ? Wkt : Wvt;
  const float* bias        = z == 0 ? bq : z == 1 ? bk : bv;
  unsigned short* Cout     = z == 0 ? Qb : z == 1 ? Kb : Vtb;
  const int K = Dv, N = Dv;

  const int tid = threadIdx.x;
  const int l = tid & 63, w = tid >> 6;
  const int wr = w >> 1, wc = w & 1;
  const int m0 = blockIdx.y * 128, n0 = blockIdx.x * 128;
  const int lr = l & 15, kk = (l >> 4) * 8;
  const int srow = tid >> 2, soff = (tid & 3) * 8;

  const unsigned short* Ag = A + (size_t)(m0 + srow) * K + soff;
  const unsigned short* Bg = Bt + (size_t)(n0 + srow) * K + soff;
  unsigned short* AsD = &As[tid * 8];
  unsigned short* BsD = &Bs[tid * 8];

  f32x4 acc[4][4] = {};

  for (int k0 = 0; k0 < K; k0 += 32) {
    __syncthreads();
    gload_lds16(Ag + k0, AsD);
    gload_lds16(Ag + (size_t)64 * K + k0, AsD + 2048);
    gload_lds16(Bg + k0, BsD);
    gload_lds16(Bg + (size_t)64 * K + k0, BsD + 2048);
    __syncthreads();
    short8 af[4], bf[4];
#pragma unroll
    for (int m = 0; m < 4; m++) af[m] = *(const short8*)&As[(wr * 64 + m * 16 + lr) * 32 + kk];
#pragma unroll
    for (int n = 0; n < 4; n++) bf[n] = *(const short8*)&Bs[(wc * 64 + n * 16 + lr) * 32 + kk];
    __builtin_amdgcn_s_setprio(1);
#pragma unroll
    for (int m = 0; m < 4; m++)
#pragma unroll
      for (int n = 0; n < 4; n++)
        acc[m][n] = __builtin_amdgcn_mfma_f32_16x16x32_bf16(af[m], bf[n], acc[m][n], 0, 0, 0);
    __builtin_amdgcn_s_setprio(0);
  }

#pragma unroll
  for (int m = 0; m < 4; m++) {
    const int row_base = m0 + wr * 64 + m * 16 + (l >> 4) * 4;
#pragma unroll
    for (int n = 0; n < 4; n++) {
      const int col = n0 + wc * 64 + n * 16 + lr;
      const float bv4 = bias[col];
      if (z == 2) {
        const int h = col >> 6, hd = col & 63;
        const int bb = row_base >> 10, j = row_base & 1023;
        unsigned short t4[4];
#pragma unroll
        for (int r = 0; r < 4; r++) t4[r] = f2bf(acc[m][n][r] + bv4);
        *(uint2*)&Cout[((size_t)((bb * 16 + h) * 64 + hd)) * 1024 + j] = *(const uint2*)t4;
      } else {
#pragma unroll
        for (int r = 0; r < 4; r++)
          Cout[(size_t)(row_base + r) * N + col] = f2bf(acc[m][n][r] + bv4);
      }
    }
  }
}

// ---------------- O-proj NT GEMM: 64x128 tile, fp32 out --------------------
__global__ __launch_bounds__(256) void k_gemmO(const unsigned short* __restrict__ A,
                                               const unsigned short* __restrict__ Bt,
                                               const float* __restrict__ bias,
                                               float* __restrict__ Cout) {
  __shared__ unsigned short As[64 * 32];
  __shared__ unsigned short Bs[128 * 32];
  const int K = Dv, N = Dv;
  const int tid = threadIdx.x;
  const int l = tid & 63, w = tid >> 6;
  const int wr = w >> 1, wc = w & 1;
  const int m0 = blockIdx.y * 64, n0 = blockIdx.x * 128;
  const int lr = l & 15, kk = (l >> 4) * 8;
  const int srow = tid >> 2, soff = (tid & 3) * 8;

  const unsigned short* Ag = A + (size_t)(m0 + srow) * K + soff;
  const unsigned short* Bg = Bt + (size_t)(n0 + srow) * K + soff;
  unsigned short* AsD = &As[tid * 8];
  unsigned short* BsD = &Bs[tid * 8];

  f32x4 acc[2][4] = {};

  for (int k0 = 0; k0 < K; k0 += 32) {
    __syncthreads();
    gload_lds16(Ag + k0, AsD);
    gload_lds16(Bg + k0, BsD);
    gload_lds16(Bg + (size_t)64 * K + k0, BsD + 2048);
    __syncthreads();
    short8 af[2], bf[4];
#pragma unroll
    for (int m = 0; m < 2; m++) af[m] = *(const short8*)&As[(wr * 32 + m * 16 + lr) * 32 + kk];
#pragma unroll
    for (int n = 0; n < 4; n++) bf[n] = *(const short8*)&Bs[(wc * 64 + n * 16 + lr) * 32 + kk];
    __builtin_amdgcn_s_setprio(1);
#pragma unroll
    for (int m = 0; m < 2; m++)
#pragma unroll
      for (int n = 0; n < 4; n++)
        acc[m][n] = __builtin_amdgcn_mfma_f32_16x16x32_bf16(af[m], bf[n], acc[m][n], 0, 0, 0);
    __builtin_amdgcn_s_setprio(0);
  }

#pragma unroll
  for (int m = 0; m < 2; m++) {
    const int row_base = m0 + wr * 32 + m * 16 + (l >> 4) * 4;
#pragma unroll
    for (int n = 0; n < 4; n++) {
      const int col = n0 + wc * 64 + n * 16 + lr;
      const float bv4 = bias[col];
#pragma unroll
      for (int r = 0; r < 4; r++)
        Cout[(size_t)(row_base + r) * N + col] = acc[m][n][r] + bv4;
    }
  }
}

// ---------------- fused attention ------------------------------------------
// grid 1024 (XCD-chunk swizzled), 256 thr (4 waves). Wave w: 16 q-rows.
// K,V double-buffered LDS (T14 split, 1 barrier/iter). rel loads issued
// FIRST (vmcnt FIFO: Ts wait leaves K/V prefetch in flight). Ts bf16
// [80][18] (cvtpk2 u32 writes, aligned, ~2-way banks). Shared max, log2
// softmax, defer-max, deferred denominator — all R8-proven.
__global__ __launch_bounds__(256) void k_attn(const unsigned short* __restrict__ Qb,
                                              const unsigned short* __restrict__ Kb,
                                              const unsigned short* __restrict__ Vt,
                                              const unsigned short* __restrict__ relb,
                                              unsigned short* __restrict__ AO) {
  __shared__ unsigned short Ks[2][64][68];   // 17,408 B
  __shared__ unsigned short Vs[2][64][68];   // 17,408 B (Vt rows: [d][j])
  __shared__ unsigned short Tsb[4][80][18];  // 11,520 B bf16 [tb][rr]
  __shared__ unsigned short Ps[4][16][68];   //  8,704 B   -> total 55,040 B

  const int tid = threadIdx.x, l = tid & 63, w = tid >> 6;
  const int lr = l & 15, lg = l >> 4, kk = lg * 8;

  // bijective XCD-chunk swizzle: XCD k gets 8 heads' K/V (2MB) -> L2-resident
  const int raw = blockIdx.x;
  const int work = (raw & 7) * 128 + (raw >> 3);
  const int i0 = (work & 15) * 64;
  const int h = (work >> 4) & 15;
  const int b = work >> 8;

  const unsigned short* Kg  = Kb + (size_t)b * SKVv * Dv + h * HDv;
  const unsigned short* Vtg = Vt + ((size_t)(b * Hv + h) * HDv) * (size_t)SKVv;

  const unsigned short* Qg = Qb + ((size_t)(b * SQv + i0 + w * 16 + lr)) * Dv + h * HDv;
  short8 aq0 = *(const short8*)&Qg[kk];
  short8 aq1 = *(const short8*)&Qg[32 + kk];

  // staging coords: thread covers K row j0+sr / Vt row d=sr, 32B chunk sc
  const int sr = tid >> 2, sc = (tid & 3) * 16;

  // strength-reduced running pointers (next K/V tile to load)
  const unsigned short* kld = Kg + (size_t)(64 + sr) * Dv + sc;
  const unsigned short* vld = Vtg + (size_t)sr * SKVv + 64 + sc;
  // rel band pointer for tile 0: row (i0 - 0 + 960 + w*16 + lr)
  const unsigned short* relit = relb + (size_t)(i0 + 960 + w * 16 + lr) * HDv + kk;

  uint4 pk0, pk1, pv0, pv1;
  auto wrbuf = [&](int buf) {
    *(uint4*)&Ks[buf][sr][sc]     = pk0;
    *(uint4*)&Ks[buf][sr][sc + 8] = pk1;
    *(uint4*)&Vs[buf][sr][sc]     = pv0;
    *(uint4*)&Vs[buf][sr][sc + 8] = pv1;
  };

  // prologue: tile 0
  pk0 = *(const uint4*)&Kg[(size_t)sr * Dv + sc];
  pk1 = *(const uint4*)&Kg[(size_t)sr * Dv + sc + 8];
  pv0 = *(const uint4*)&Vtg[(size_t)sr * SKVv + sc];
  pv1 = *(const uint4*)&Vtg[(size_t)sr * SKVv + sc + 8];
  wrbuf(0);
  __syncthreads();

  f32x4 Oacc[4] = {};
  f32x4 vsum[4] = {};   // vsum[jf][r] (deferred denominator)
  float mrow = -3e38f;  // shared over this lane-group's 4 rows

  for (int it = 0; it < 16; ++it) {
    const int cur = it & 1;

    // rel-band loads FIRST: the Ts MFMAs' vmcnt wait then leaves the K/V
    // prefetch (issued below) still in flight (vmcnt is FIFO).
    short8 br0[5], br1[5];
#pragma unroll
    for (int tf = 0; tf < 5; tf++) {
      br0[tf] = *(const short8*)&relit[(size_t)tf * 16 * HDv];
      br1[tf] = *(const short8*)&relit[(size_t)tf * 16 * HDv + 32];
    }
    relit -= (size_t)64 * HDv;   // next iter: base drops by 64 rows

    if (it < 15) {       // T14: issue next-tile loads early, write late
      pk0 = *(const uint4*)&kld[0];
      pk1 = *(const uint4*)&kld[8];
      pv0 = *(const uint4*)&vld[0];
      pv1 = *(const uint4*)&vld[8];
      kld += (size_t)64 * Dv;
      vld += 64;
    }

    // ---- content scores S = Q K^T ----
    __builtin_amdgcn_s_setprio(1);
    f32x4 sacc[4] = {};
#pragma unroll
    for (int jf = 0; jf < 4; jf++) {
      short8 bk0 = *(const short8*)&Ks[cur][jf * 16 + lr][kk];
      short8 bk1 = *(const short8*)&Ks[cur][jf * 16 + lr][32 + kk];
      sacc[jf] = __builtin_amdgcn_mfma_f32_16x16x32_bf16(aq0, bk0, sacc[jf], 0, 0, 0);
      sacc[jf] = __builtin_amdgcn_mfma_f32_16x16x32_bf16(aq1, bk1, sacc[jf], 0, 0, 0);
    }

    // ---- rel band T -> Tsb[w][tb][rr] bf16, two u32 writes per tf ----
#pragma unroll
    for (int tf = 0; tf < 5; tf++) {
      f32x4 tacc = {};
      tacc = __builtin_amdgcn_mfma_f32_16x16x32_bf16(aq0, br0[tf], tacc, 0, 0, 0);
      tacc = __builtin_amdgcn_mfma_f32_16x16x32_bf16(aq1, br1[tf], tacc, 0, 0, 0);
      *(unsigned int*)&Tsb[w][tf * 16 + lr][4 * lg]     = cvtpk2(tacc[0], tacc[1]);
      *(unsigned int*)&Tsb[w][tf * 16 + lr][4 * lg + 2] = cvtpk2(tacc[2], tacc[3]);
    }
    __builtin_amdgcn_s_setprio(0);

    // ---- combine + softmax (log2 domain, shared max, defer-max) ----
    float p[4][4];
#pragma unroll
    for (int jf = 0; jf < 4; jf++) {
      const int jj = jf * 16 + lr;
#pragma unroll
      for (int r = 0; r < 4; r++) {
        const int rr = lg * 4 + r;
        p[jf][r] = sacc[jf][r] * C1 + bf2f(Tsb[w][rr - jj + 63][rr]);
      }
    }
    float mx = p[0][0];
#pragma unroll
    for (int jf = 0; jf < 4; jf++)
#pragma unroll
      for (int r = 0; r < 4; r++) mx = fmaxf(mx, p[jf][r]);
    mx = red16_max(mx);
    if (__any(mx > mrow + THR2)) {
      const float mnew = fmaxf(mrow, mx);
      const float rs = __builtin_amdgcn_exp2f(mrow - mnew);
      mrow = mnew;
#pragma unroll
      for (int q4 = 0; q4 < 4; q4++) { vsum[q4] *= rs; Oacc[q4] *= rs; }
    }
#pragma unroll
    for (int jf = 0; jf < 4; jf++)
#pragma unroll
      for (int r = 0; r < 4; r++) {
        const float e = __builtin_amdgcn_exp2f(p[jf][r] - mrow);
        vsum[jf][r] += e;
        Ps[w][lg * 4 + r][jf * 16 + lr] = cvtpk1(e);
      }

    // ---- O += P V ----
    short8 ap0 = *(const short8*)&Ps[w][lr][kk];
    short8 ap1 = *(const short8*)&Ps[w][lr][32 + kk];
    __builtin_amdgcn_s_setprio(1);
#pragma unroll
    for (int df = 0; df < 4; df++) {
      short8 bv0 = *(const short8*)&Vs[cur][df * 16 + lr][kk];
      short8 bv1 = *(const short8*)&Vs[cur][df * 16 + lr][32 + kk];
      Oacc[df] = __builtin_amdgcn_mfma_f32_16x16x32_bf16(ap0, bv0, Oacc[df], 0, 0, 0);
      Oacc[df] = __builtin_amdgcn_mfma_f32_16x16x32_bf16(ap1, bv1, Oacc[df], 0, 0, 0);
    }
    __builtin_amdgcn_s_setprio(0);

    if (it < 15) wrbuf(cur ^ 1);  // write-late half of T14 split
    __syncthreads();
  }

  // ---- epilogue: deferred denominator, normalize, write ----
#pragma unroll
  for (int r = 0; r < 4; r++) {
    float s = vsum[0][r] + vsum[1][r] + vsum[2][r] + vsum[3][r];
    s = red16_sum(s);
    const float inv = 1.f / s;
    const size_t row = (size_t)(b * SQv + i0 + w * 16 + lg * 4 + r) * Dv + h * HDv;
#pragma unroll
    for (int df = 0; df < 4; df++)
      AO[row + df * 16 + lr] = cvtpk1(Oacc[df][r] * inv);
  }
}

// ---------------------------------------------------------------------------
extern "C" void kernel_launch(void* const* d_in, const int* in_sizes, int n_in,
                              void* d_out, int out_size, void* d_ws, size_t ws_size,
                              hipStream_t stream) {
  const float* query = (const float*)d_in[0];
  const float* keyv  = (const float*)d_in[1];
  const float* Wq    = (const float*)d_in[2];
  const float* bq    = (const float*)d_in[3];
  const float* Wk    = (const float*)d_in[4];
  const float* bk    = (const float*)d_in[5];
  const float* Wv    = (const float*)d_in[6];
  const float* bv    = (const float*)d_in[7];
  const float* Wo    = (const float*)d_in[8];
  const float* bo    = (const float*)d_in[9];
  const float* rel   = (const float*)d_in[10];

  char* ws = (char*)d_ws;
  unsigned short* qb   = (unsigned short*)(ws + OFF_QB);
  unsigned short* kvb  = (unsigned short*)(ws + OFF_KVB);
  unsigned short* Wqt  = (unsigned short*)(ws + OFF_WQT);
  unsigned short* Wkt  = (unsigned short*)(ws + OFF_WKT);
  unsigned short* Wvt  = (unsigned short*)(ws + OFF_WVT);
  unsigned short* Wot  = (unsigned short*)(ws + OFF_WOT);
  unsigned short* relb = (unsigned short*)(ws + OFF_REL);
  unsigned short* Qb   = (unsigned short*)(ws + OFF_Q);
  unsigned short* Kb   = (unsigned short*)(ws + OFF_K);
  unsigned short* Vtb  = (unsigned short*)(ws + OFF_V);
  unsigned short* AOb  = (unsigned short*)(ws + OFF_AO);

  k_prep<<<5184, 256, 0, stream>>>(query, keyv, rel, Wq, Wk, Wv, Wo,
                                   qb, kvb, relb, Wqt, Wkt, Wvt, Wot);

  dim3 g3(Dv / 128, (Bz * SQv) / 128, 3);  // 768 blocks
  k_gemm3<<<g3, 256, 0, stream>>>(qb, kvb, Wqt, Wkt, Wvt, bq, bk, bv, Qb, Kb, Vtb);

  k_attn<<<1024, 256, 0, stream>>>(Qb, Kb, Vtb, relb, AOb);

  dim3 go(Dv / 128, (Bz * SQv) / 64);  // 512 blocks
  k_gemmO<<<go, 256, 0, stream>>>(AOb, Wot, bo, (float*)d_out);
}

// Round 15
// 174.290 us; speedup vs baseline: 1.0431x; 1.0007x over previous
//
#include <hip/hip_runtime.h>
#include <hip/hip_bf16.h>
#include <stdint.h>

// ---------------------------------------------------------------------------
// RelativeCrossAttention: B=4, SQ=SKV=1024, D=1024, H=16, HD=64, MAXL=1024
// FINAL (= R12, best verified): bf16-MFMA pipeline.
//   k_prep  : fused fp32->bf16 cvt (q, kv, rel*log2e) + 4 weight transposes
//   k_gemm3 : merged Q/K/V projection NT GEMMs (z=0,1,2), 128x128 tile,
//             global_load_lds staging; V written pre-transposed per head
//   k_attn  : flash-style attention w/ relative-position band bias
//             (T = Q @ rel_band^T via MFMA, gathered at rr-jj+63),
//             K+V double-buffered LDS (T14 split, 1 barrier/iter),
//             log2-domain softmax, shared 4-row max, defer-max (THR2),
//             deferred denominator, bf16 Ts [80][18], XCD-chunk swizzle
//   k_gemmO : output projection, 64x128 tile, fp32 out
// Session evidence: all LDS vector-access row strides must be == 0/8 mod 16
// bytes (132B-stride b128 access fails: R13); multi-part attn restructures
// failed 6x unexplained -> this is the proven-frontier configuration.
// 174.4 us, absmax 0.0254 (threshold 0.0309).
// ---------------------------------------------------------------------------

typedef __attribute__((ext_vector_type(8))) short short8;
typedef __attribute__((ext_vector_type(4))) float f32x4;

constexpr int Bz = 4, SQv = 1024, SKVv = 1024, Dv = 1024, Hv = 16, HDv = 64;
constexpr float LOG2E = 1.4426950408889634f;
constexpr float C1 = 0.125f * LOG2E;     // SCALE * log2e (QK path)
constexpr float THR2 = 11.5f;            // defer-max threshold (log2 units)

// workspace offsets (bytes)
constexpr size_t OFF_QB  = 0;
constexpr size_t OFF_KVB = 8388608;
constexpr size_t OFF_WQT = 16777216;
constexpr size_t OFF_WKT = 18874368;
constexpr size_t OFF_WVT = 20971520;
constexpr size_t OFF_WOT = 23068672;
constexpr size_t OFF_REL = 25165824;   // rel*log2e bf16 [2048][64]
constexpr size_t OFF_Q   = 25427968;
constexpr size_t OFF_K   = 33816576;
constexpr size_t OFF_V   = 42205184;   // V^T bf16 [(b*16+h)*64+d][1024]
constexpr size_t OFF_AO  = 50593792;

__device__ __forceinline__ unsigned short f2bf(float f) {
  union { float f; unsigned int u; } v; v.f = f;
  unsigned int r = (v.u + 0x7fffu + ((v.u >> 16) & 1u)) >> 16;
  return (unsigned short)r;
}

__device__ __forceinline__ float bf2f(unsigned short u) {
  union { unsigned int i; float f; } v; v.i = (unsigned int)u << 16;
  return v.f;
}

__device__ __forceinline__ unsigned short cvtpk1(float x) {
  unsigned int r;
  asm("v_cvt_pk_bf16_f32 %0, %1, %1" : "=v"(r) : "v"(x));
  return (unsigned short)r;
}

__device__ __forceinline__ unsigned int cvtpk2(float lo, float hi) {
  unsigned int r;
  asm("v_cvt_pk_bf16_f32 %0, %1, %2" : "=v"(r) : "v"(lo), "v"(hi));
  return r;
}

__device__ __forceinline__ void gload_lds16(const unsigned short* g, unsigned short* l) {
  __builtin_amdgcn_global_load_lds(
      (const __attribute__((address_space(1))) unsigned int*)g,
      (__attribute__((address_space(3))) unsigned int*)l, 16, 0, 0);
}

template <int CTRL>
__device__ __forceinline__ float dpp_ror(float v) {
  int x = __builtin_amdgcn_update_dpp(__builtin_bit_cast(int, v),
                                      __builtin_bit_cast(int, v),
                                      CTRL, 0xf, 0xf, false);
  return __builtin_bit_cast(float, x);
}
__device__ __forceinline__ float red16_max(float v) {
  v = fmaxf(v, dpp_ror<0x121>(v));
  v = fmaxf(v, dpp_ror<0x122>(v));
  v = fmaxf(v, dpp_ror<0x124>(v));
  v = fmaxf(v, dpp_ror<0x128>(v));
  return v;
}
__device__ __forceinline__ float red16_sum(float v) {
  v += dpp_ror<0x121>(v);
  v += dpp_ror<0x122>(v);
  v += dpp_ror<0x124>(v);
  v += dpp_ror<0x128>(v);
  return v;
}

// ---------------- fused prep: cvt q/kv/rel + transpose 4 weights -----------
__global__ __launch_bounds__(256) void k_prep(const float* __restrict__ q,
                                              const float* __restrict__ kv,
                                              const float* __restrict__ rel,
                                              const float* __restrict__ Wq,
                                              const float* __restrict__ Wk,
                                              const float* __restrict__ Wv,
                                              const float* __restrict__ Wo,
                                              unsigned short* __restrict__ qb,
                                              unsigned short* __restrict__ kvb,
                                              unsigned short* __restrict__ relb,
                                              unsigned short* __restrict__ Wqt,
                                              unsigned short* __restrict__ Wkt,
                                              unsigned short* __restrict__ Wvt,
                                              unsigned short* __restrict__ Wot) {
  __shared__ unsigned short t[64][72];
  const int bx = blockIdx.x;
  if (bx < 4096) {
    const float* s = bx < 2048 ? q : kv;
    unsigned short* d = bx < 2048 ? qb : kvb;
    const int base = (bx & 2047) * 2048 + threadIdx.x * 8;
    float4 f0 = *(const float4*)(s + base);
    float4 f1 = *(const float4*)(s + base + 4);
    unsigned short o[8] = {f2bf(f0.x), f2bf(f0.y), f2bf(f0.z), f2bf(f0.w),
                           f2bf(f1.x), f2bf(f1.y), f2bf(f1.z), f2bf(f1.w)};
    *(uint4*)(d + base) = *(const uint4*)o;
    return;
  }
  if (bx < 4160) {
    const int i = (bx - 4096) * 2048 + threadIdx.x * 8;
    const int nsrc = 2047 * 64;
    unsigned short o[8];
    if (i + 8 <= nsrc) {
      float4 f0 = *(const float4*)(rel + i);
      float4 f1 = *(const float4*)(rel + i + 4);
      o[0]=f2bf(f0.x*LOG2E); o[1]=f2bf(f0.y*LOG2E); o[2]=f2bf(f0.z*LOG2E); o[3]=f2bf(f0.w*LOG2E);
      o[4]=f2bf(f1.x*LOG2E); o[5]=f2bf(f1.y*LOG2E); o[6]=f2bf(f1.z*LOG2E); o[7]=f2bf(f1.w*LOG2E);
    } else {
#pragma unroll
      for (int k = 0; k < 8; k++) o[k] = (i + k < nsrc) ? f2bf(rel[i + k]*LOG2E) : (unsigned short)0;
    }
    *(uint4*)(relb + i) = *(const uint4*)o;
    return;
  }
  const int tt = bx - 4160;
  const int z = tt >> 8, tile = tt & 255;
  const float* W = z == 0 ? Wq : z == 1 ? Wk : z == 2 ? Wv : Wo;
  unsigned short* Wt = z == 0 ? Wqt : z == 1 ? Wkt : z == 2 ? Wvt : Wot;
  const int r0 = (tile >> 4) * 64, c0 = (tile & 15) * 64;
  const int tid = threadIdx.x;
  const int r = tid >> 2, cc = (tid & 3) * 16;
  const float* src = W + (size_t)(r0 + r) * Dv + c0 + cc;
#pragma unroll
  for (int i = 0; i < 16; i += 4) {
    float4 f = *(const float4*)(src + i);
    t[r][cc + i + 0] = f2bf(f.x);
    t[r][cc + i + 1] = f2bf(f.y);
    t[r][cc + i + 2] = f2bf(f.z);
    t[r][cc + i + 3] = f2bf(f.w);
  }
  __syncthreads();
  unsigned short tmp[16];
#pragma unroll
  for (int i = 0; i < 16; i++) tmp[i] = t[cc + i][r];
  unsigned short* dstp = Wt + (size_t)(c0 + r) * Dv + r0 + cc;
  *(uint4*)(dstp)     = *(const uint4*)&tmp[0];
  *((uint4*)dstp + 1) = *(const uint4*)&tmp[8];
}

// ---------------- merged QKV NT GEMM (z = 0,1,2), 128x128 tile -------------
__global__ __launch_bounds__(256) void k_gemm3(const unsigned short* __restrict__ qb,
                                               const unsigned short* __restrict__ kvb,
                                               const unsigned short* __restrict__ Wqt,
                                               const unsigned short* __restrict__ Wkt,
                                               const unsigned short* __restrict__ Wvt,
                                               const float* __restrict__ bq,
                                               const float* __restrict__ bk,
                                               const float* __restrict__ bv,
                                               unsigned short* __restrict__ Qb,
                                               unsigned short* __restrict__ Kb,
                                               unsigned short* __restrict__ Vtb) {
  __shared__ unsigned short As[128 * 32];
  __shared__ unsigned short Bs[128 * 32];
  const int z = blockIdx.z;
  const unsigned short* A  = z == 0 ? qb : kvb;
  const unsigned short* Bt = z == 0 ? Wqt : z == 1 ? Wkt : Wvt;
  const float* bias        = z == 0 ? bq : z == 1 ? bk : bv;
  unsigned short* Cout     = z == 0 ? Qb : z == 1 ? Kb : Vtb;
  const int K = Dv, N = Dv;

  const int tid = threadIdx.x;
  const int l = tid & 63, w = tid >> 6;
  const int wr = w >> 1, wc = w & 1;
  const int m0 = blockIdx.y * 128, n0 = blockIdx.x * 128;
  const int lr = l & 15, kk = (l >> 4) * 8;
  const int srow = tid >> 2, soff = (tid & 3) * 8;

  const unsigned short* Ag = A + (size_t)(m0 + srow) * K + soff;
  const unsigned short* Bg = Bt + (size_t)(n0 + srow) * K + soff;
  unsigned short* AsD = &As[tid * 8];
  unsigned short* BsD = &Bs[tid * 8];

  f32x4 acc[4][4] = {};

  for (int k0 = 0; k0 < K; k0 += 32) {
    __syncthreads();
    gload_lds16(Ag + k0, AsD);
    gload_lds16(Ag + (size_t)64 * K + k0, AsD + 2048);
    gload_lds16(Bg + k0, BsD);
    gload_lds16(Bg + (size_t)64 * K + k0, BsD + 2048);
    __syncthreads();
    short8 af[4], bf[4];
#pragma unroll
    for (int m = 0; m < 4; m++) af[m] = *(const short8*)&As[(wr * 64 + m * 16 + lr) * 32 + kk];
#pragma unroll
    for (int n = 0; n < 4; n++) bf[n] = *(const short8*)&Bs[(wc * 64 + n * 16 + lr) * 32 + kk];
    __builtin_amdgcn_s_setprio(1);
#pragma unroll
    for (int m = 0; m < 4; m++)
#pragma unroll
      for (int n = 0; n < 4; n++)
        acc[m][n] = __builtin_amdgcn_mfma_f32_16x16x32_bf16(af[m], bf[n], acc[m][n], 0, 0, 0);
    __builtin_amdgcn_s_setprio(0);
  }

#pragma unroll
  for (int m = 0; m < 4; m++) {
    const int row_base = m0 + wr * 64 + m * 16 + (l >> 4) * 4;
#pragma unroll
    for (int n = 0; n < 4; n++) {
      const int col = n0 + wc * 64 + n * 16 + lr;
      const float bv4 = bias[col];
      if (z == 2) {
        const int h = col >> 6, hd = col & 63;
        const int bb = row_base >> 10, j = row_base & 1023;
        unsigned short t4[4];
#pragma unroll
        for (int r = 0; r < 4; r++) t4[r] = f2bf(acc[m][n][r] + bv4);
        *(uint2*)&Cout[((size_t)((bb * 16 + h) * 64 + hd)) * 1024 + j] = *(const uint2*)t4;
      } else {
#pragma unroll
        for (int r = 0; r < 4; r++)
          Cout[(size_t)(row_base + r) * N + col] = f2bf(acc[m][n][r] + bv4);
      }
    }
  }
}

// ---------------- O-proj NT GEMM: 64x128 tile, fp32 out --------------------
__global__ __launch_bounds__(256) void k_gemmO(const unsigned short* __restrict__ A,
                                               const unsigned short* __restrict__ Bt,
                                               const float* __restrict__ bias,
                                               float* __restrict__ Cout) {
  __shared__ unsigned short As[64 * 32];
  __shared__ unsigned short Bs[128 * 32];
  const int K = Dv, N = Dv;
  const int tid = threadIdx.x;
  const int l = tid & 63, w = tid >> 6;
  const int wr = w >> 1, wc = w & 1;
  const int m0 = blockIdx.y * 64, n0 = blockIdx.x * 128;
  const int lr = l & 15, kk = (l >> 4) * 8;
  const int srow = tid >> 2, soff = (tid & 3) * 8;

  const unsigned short* Ag = A + (size_t)(m0 + srow) * K + soff;
  const unsigned short* Bg = Bt + (size_t)(n0 + srow) * K + soff;
  unsigned short* AsD = &As[tid * 8];
  unsigned short* BsD = &Bs[tid * 8];

  f32x4 acc[2][4] = {};

  for (int k0 = 0; k0 < K; k0 += 32) {
    __syncthreads();
    gload_lds16(Ag + k0, AsD);
    gload_lds16(Bg + k0, BsD);
    gload_lds16(Bg + (size_t)64 * K + k0, BsD + 2048);
    __syncthreads();
    short8 af[2], bf[4];
#pragma unroll
    for (int m = 0; m < 2; m++) af[m] = *(const short8*)&As[(wr * 32 + m * 16 + lr) * 32 + kk];
#pragma unroll
    for (int n = 0; n < 4; n++) bf[n] = *(const short8*)&Bs[(wc * 64 + n * 16 + lr) * 32 + kk];
    __builtin_amdgcn_s_setprio(1);
#pragma unroll
    for (int m = 0; m < 2; m++)
#pragma unroll
      for (int n = 0; n < 4; n++)
        acc[m][n] = __builtin_amdgcn_mfma_f32_16x16x32_bf16(af[m], bf[n], acc[m][n], 0, 0, 0);
    __builtin_amdgcn_s_setprio(0);
  }

#pragma unroll
  for (int m = 0; m < 2; m++) {
    const int row_base = m0 + wr * 32 + m * 16 + (l >> 4) * 4;
#pragma unroll
    for (int n = 0; n < 4; n++) {
      const int col = n0 + wc * 64 + n * 16 + lr;
      const float bv4 = bias[col];
#pragma unroll
      for (int r = 0; r < 4; r++)
        Cout[(size_t)(row_base + r) * N + col] = acc[m][n][r] + bv4;
    }
  }
}

// ---------------- fused attention ------------------------------------------
// grid 1024 (XCD-chunk swizzled), 256 thr (4 waves). Wave w: 16 q-rows.
// K,V double-buffered LDS (T14 split, 1 barrier/iter). rel loads issued
// FIRST (vmcnt FIFO). Ts bf16 [80][18]. Log2 softmax, shared max,
// defer-max, deferred denominator.
__global__ __launch_bounds__(256) void k_attn(const unsigned short* __restrict__ Qb,
                                              const unsigned short* __restrict__ Kb,
                                              const unsigned short* __restrict__ Vt,
                                              const unsigned short* __restrict__ relb,
                                              unsigned short* __restrict__ AO) {
  __shared__ unsigned short Ks[2][64][68];   // 17,408 B
  __shared__ unsigned short Vs[2][64][68];   // 17,408 B (Vt rows: [d][j])
  __shared__ unsigned short Tsb[4][80][18];  // 11,520 B bf16 [tb][rr]
  __shared__ unsigned short Ps[4][16][68];   //  8,704 B   -> total 55,040 B

  const int tid = threadIdx.x, l = tid & 63, w = tid >> 6;
  const int lr = l & 15, lg = l >> 4, kk = lg * 8;

  // bijective XCD-chunk swizzle: XCD k gets 8 heads' K/V (2MB) -> L2-resident
  const int raw = blockIdx.x;
  const int work = (raw & 7) * 128 + (raw >> 3);
  const int i0 = (work & 15) * 64;
  const int h = (work >> 4) & 15;
  const int b = work >> 8;

  const unsigned short* Kg  = Kb + (size_t)b * SKVv * Dv + h * HDv;
  const unsigned short* Vtg = Vt + ((size_t)(b * Hv + h) * HDv) * (size_t)SKVv;

  const unsigned short* Qg = Qb + ((size_t)(b * SQv + i0 + w * 16 + lr)) * Dv + h * HDv;
  short8 aq0 = *(const short8*)&Qg[kk];
  short8 aq1 = *(const short8*)&Qg[32 + kk];

  // staging coords: thread covers K row j0+sr / Vt row d=sr, 32B chunk sc
  const int sr = tid >> 2, sc = (tid & 3) * 16;

  // strength-reduced running pointers (next K/V tile to load)
  const unsigned short* kld = Kg + (size_t)(64 + sr) * Dv + sc;
  const unsigned short* vld = Vtg + (size_t)sr * SKVv + 64 + sc;
  // rel band pointer for tile 0: row (i0 - 0 + 960 + w*16 + lr)
  const unsigned short* relit = relb + (size_t)(i0 + 960 + w * 16 + lr) * HDv + kk;

  uint4 pk0, pk1, pv0, pv1;
  auto wrbuf = [&](int buf) {
    *(uint4*)&Ks[buf][sr][sc]     = pk0;
    *(uint4*)&Ks[buf][sr][sc + 8] = pk1;
    *(uint4*)&Vs[buf][sr][sc]     = pv0;
    *(uint4*)&Vs[buf][sr][sc + 8] = pv1;
  };

  // prologue: tile 0
  pk0 = *(const uint4*)&Kg[(size_t)sr * Dv + sc];
  pk1 = *(const uint4*)&Kg[(size_t)sr * Dv + sc + 8];
  pv0 = *(const uint4*)&Vtg[(size_t)sr * SKVv + sc];
  pv1 = *(const uint4*)&Vtg[(size_t)sr * SKVv + sc + 8];
  wrbuf(0);
  __syncthreads();

  f32x4 Oacc[4] = {};
  f32x4 vsum[4] = {};   // vsum[jf][r] (deferred denominator)
  float mrow = -3e38f;  // shared over this lane-group's 4 rows

  for (int it = 0; it < 16; ++it) {
    const int cur = it & 1;

    // rel-band loads FIRST: the Ts MFMAs' vmcnt wait then leaves the K/V
    // prefetch (issued below) still in flight (vmcnt is FIFO).
    short8 br0[5], br1[5];
#pragma unroll
    for (int tf = 0; tf < 5; tf++) {
      br0[tf] = *(const short8*)&relit[(size_t)tf * 16 * HDv];
      br1[tf] = *(const short8*)&relit[(size_t)tf * 16 * HDv + 32];
    }
    relit -= (size_t)64 * HDv;   // next iter: base drops by 64 rows

    if (it < 15) {       // T14: issue next-tile loads early, write late
      pk0 = *(const uint4*)&kld[0];
      pk1 = *(const uint4*)&kld[8];
      pv0 = *(const uint4*)&vld[0];
      pv1 = *(const uint4*)&vld[8];
      kld += (size_t)64 * Dv;
      vld += 64;
    }

    // ---- content scores S = Q K^T ----
    __builtin_amdgcn_s_setprio(1);
    f32x4 sacc[4] = {};
#pragma unroll
    for (int jf = 0; jf < 4; jf++) {
      short8 bk0 = *(const short8*)&Ks[cur][jf * 16 + lr][kk];
      short8 bk1 = *(const short8*)&Ks[cur][jf * 16 + lr][32 + kk];
      sacc[jf] = __builtin_amdgcn_mfma_f32_16x16x32_bf16(aq0, bk0, sacc[jf], 0, 0, 0);
      sacc[jf] = __builtin_amdgcn_mfma_f32_16x16x32_bf16(aq1, bk1, sacc[jf], 0, 0, 0);
    }

    // ---- rel band T -> Tsb[w][tb][rr] bf16, two u32 writes per tf ----
#pragma unroll
    for (int tf = 0; tf < 5; tf++) {
      f32x4 tacc = {};
      tacc = __builtin_amdgcn_mfma_f32_16x16x32_bf16(aq0, br0[tf], tacc, 0, 0, 0);
      tacc = __builtin_amdgcn_mfma_f32_16x16x32_bf16(aq1, br1[tf], tacc, 0, 0, 0);
      *(unsigned int*)&Tsb[w][tf * 16 + lr][4 * lg]     = cvtpk2(tacc[0], tacc[1]);
      *(unsigned int*)&Tsb[w][tf * 16 + lr][4 * lg + 2] = cvtpk2(tacc[2], tacc[3]);
    }
    __builtin_amdgcn_s_setprio(0);

    // ---- combine + softmax (log2 domain, shared max, defer-max) ----
    float p[4][4];
#pragma unroll
    for (int jf = 0; jf < 4; jf++) {
      const int jj = jf * 16 + lr;
#pragma unroll
      for (int r = 0; r < 4; r++) {
        const int rr = lg * 4 + r;
        p[jf][r] = sacc[jf][r] * C1 + bf2f(Tsb[w][rr - jj + 63][rr]);
      }
    }
    float mx = p[0][0];
#pragma unroll
    for (int jf = 0; jf < 4; jf++)
#pragma unroll
      for (int r = 0; r < 4; r++) mx = fmaxf(mx, p[jf][r]);
    mx = red16_max(mx);
    if (__any(mx > mrow + THR2)) {
      const float mnew = fmaxf(mrow, mx);
      const float rs = __builtin_amdgcn_exp2f(mrow - mnew);
      mrow = mnew;
#pragma unroll
      for (int q4 = 0; q4 < 4; q4++) { vsum[q4] *= rs; Oacc[q4] *= rs; }
    }
#pragma unroll
    for (int jf = 0; jf < 4; jf++)
#pragma unroll
      for (int r = 0; r < 4; r++) {
        const float e = __builtin_amdgcn_exp2f(p[jf][r] - mrow);
        vsum[jf][r] += e;
        Ps[w][lg * 4 + r][jf * 16 + lr] = cvtpk1(e);
      }

    // ---- O += P V ----
    short8 ap0 = *(const short8*)&Ps[w][lr][kk];
    short8 ap1 = *(const short8*)&Ps[w][lr][32 + kk];
    __builtin_amdgcn_s_setprio(1);
#pragma unroll
    for (int df = 0; df < 4; df++) {
      short8 bv0 = *(const short8*)&Vs[cur][df * 16 + lr][kk];
      short8 bv1 = *(const short8*)&Vs[cur][df * 16 + lr][32 + kk];
      Oacc[df] = __builtin_amdgcn_mfma_f32_16x16x32_bf16(ap0, bv0, Oacc[df], 0, 0, 0);
      Oacc[df] = __builtin_amdgcn_mfma_f32_16x16x32_bf16(ap1, bv1, Oacc[df], 0, 0, 0);
    }
    __builtin_amdgcn_s_setprio(0);

    if (it < 15) wrbuf(cur ^ 1);  // write-late half of T14 split
    __syncthreads();
  }

  // ---- epilogue: deferred denominator, normalize, write ----
#pragma unroll
  for (int r = 0; r < 4; r++) {
    float s = vsum[0][r] + vsum[1][r] + vsum[2][r] + vsum[3][r];
    s = red16_sum(s);
    const float inv = 1.f / s;
    const size_t row = (size_t)(b * SQv + i0 + w * 16 + lg * 4 + r) * Dv + h * HDv;
#pragma unroll
    for (int df = 0; df < 4; df++)
      AO[row + df * 16 + lr] = cvtpk1(Oacc[df][r] * inv);
  }
}

// ---------------------------------------------------------------------------
extern "C" void kernel_launch(void* const* d_in, const int* in_sizes, int n_in,
                              void* d_out, int out_size, void* d_ws, size_t ws_size,
                              hipStream_t stream) {
  const float* query = (const float*)d_in[0];
  const float* keyv  = (const float*)d_in[1];
  const float* Wq    = (const float*)d_in[2];
  const float* bq    = (const float*)d_in[3];
  const float* Wk    = (const float*)d_in[4];
  const float* bk    = (const float*)d_in[5];
  const float* Wv    = (const float*)d_in[6];
  const float* bv    = (const float*)d_in[7];
  const float* Wo    = (const float*)d_in[8];
  const float* bo    = (const float*)d_in[9];
  const float* rel   = (const float*)d_in[10];

  char* ws = (char*)d_ws;
  unsigned short* qb   = (unsigned short*)(ws + OFF_QB);
  unsigned short* kvb  = (unsigned short*)(ws + OFF_KVB);
  unsigned short* Wqt  = (unsigned short*)(ws + OFF_WQT);
  unsigned short* Wkt  = (unsigned short*)(ws + OFF_WKT);
  unsigned short* Wvt  = (unsigned short*)(ws + OFF_WVT);
  unsigned short* Wot  = (unsigned short*)(ws + OFF_WOT);
  unsigned short* relb = (unsigned short*)(ws + OFF_REL);
  unsigned short* Qb   = (unsigned short*)(ws + OFF_Q);
  unsigned short* Kb   = (unsigned short*)(ws + OFF_K);
  unsigned short* Vtb  = (unsigned short*)(ws + OFF_V);
  unsigned short* AOb  = (unsigned short*)(ws + OFF_AO);

  k_prep<<<5184, 256, 0, stream>>>(query, keyv, rel, Wq, Wk, Wv, Wo,
                                   qb, kvb, relb, Wqt, Wkt, Wvt, Wot);

  dim3 g3(Dv / 128, (Bz * SQv) / 128, 3);  // 768 blocks
  k_gemm3<<<g3, 256, 0, stream>>>(qb, kvb, Wqt, Wkt, Wvt, bq, bk, bv, Qb, Kb, Vtb);

  k_attn<<<1024, 256, 0, stream>>>(Qb, Kb, Vtb, relb, AOb);

  dim3 go(Dv / 128, (Bz * SQv) / 64);  // 512 blocks
  k_gemmO<<<go, 256, 0, stream>>>(AOb, Wot, bo, (float*)d_out);
}